// Round 4
// baseline (166.716 us; speedup 1.0000x reference)
//
#include <hip/hip_runtime.h>
#include <math.h>

#define NATOMS 10000
#define NEDGES 200000

// Row layout per edge (60 values, receiver-sorted CSR order):
//   l0: ofs 0,  n=0..7,  m=0      (8)   [sh0 constant folded in]
//   l1: ofs 8,  n=0..5,  m=0..2   (18)
//   l2: ofs 26, n=0..3,  m=0..4   (20)
//   l3: ofs 46, n=0..1,  m=0..6   (14)
// W2 layout (floats): l0 @0 (4096 = (s*8+n)*128+j), l1 @4096 (3072),
//                     l2 @7168 (2048), l3 @9216 (1024); total 10240.

__device__ __forceinline__ unsigned short f2bf(float f) {
    unsigned int u = __float_as_uint(f);
    // round-to-nearest-even
    u += 0x7FFFu + ((u >> 16) & 1u);
    return (unsigned short)(u >> 16);
}

__device__ __forceinline__ float bf2f(unsigned short h) {
    return __uint_as_float(((unsigned int)h) << 16);
}

__global__ __launch_bounds__(256) void prep_w2_kernel(
    const float* __restrict__ emb,
    const float* __restrict__ wm0, const float* __restrict__ wm1,
    const float* __restrict__ wm2, const float* __restrict__ wm3,
    float* __restrict__ W2)
{
    int tid = blockIdx.x * 256 + threadIdx.x;
    if (tid >= 10240) return;
    const float* wm; int idx, Nl;
    if (tid < 4096)      { wm = wm0; idx = tid;        Nl = 8; }
    else if (tid < 7168) { wm = wm1; idx = tid - 4096; Nl = 6; }
    else if (tid < 9216) { wm = wm2; idx = tid - 7168; Nl = 4; }
    else                 { wm = wm3; idx = tid - 9216; Nl = 2; }
    int j  = idx & 127;
    int sn = idx >> 7;
    int n  = sn % Nl;
    int s  = sn / Nl;
    float acc = 0.0f;
    #pragma unroll
    for (int c = 0; c < 16; ++c)
        acc = fmaf(wm[(n*16 + c)*128 + j], emb[s*16 + c], acc);
    W2[tid] = acc;
}

__global__ __launch_bounds__(256) void count_kernel(
    const int* __restrict__ receivers, int* __restrict__ counts)
{
    int e = blockIdx.x * 256 + threadIdx.x;
    if (e < NEDGES) atomicAdd(&counts[receivers[e]], 1);
}

__global__ __launch_bounds__(1024) void scan_kernel(
    const int* __restrict__ counts, int* __restrict__ offsets,
    int* __restrict__ cursor)
{
    __shared__ int psum[1024];
    const int t = threadIdx.x;
    int local[10];
    int sum = 0;
    #pragma unroll
    for (int k = 0; k < 10; ++k) {
        int idx = t * 10 + k;
        int c = (idx < NATOMS) ? counts[idx] : 0;
        local[k] = sum;
        sum += c;
    }
    psum[t] = sum;
    __syncthreads();
    for (int off = 1; off < 1024; off <<= 1) {
        int v = (t >= off) ? psum[t - off] : 0;
        __syncthreads();
        psum[t] += v;
        __syncthreads();
    }
    int base = (t > 0) ? psum[t - 1] : 0;
    #pragma unroll
    for (int k = 0; k < 10; ++k) {
        int idx = t * 10 + k;
        if (idx < NATOMS) {
            offsets[idx] = base + local[k];
            cursor[idx]  = base + local[k];
        }
    }
    if (t == 0) offsets[NATOMS] = NEDGES;
}

__global__ __launch_bounds__(256) void scatter_kernel(
    const int* __restrict__ receivers, int* __restrict__ cursor,
    int* __restrict__ csr)
{
    int e = blockIdx.x * 256 + threadIdx.x;
    if (e < NEDGES) {
        int p = atomicAdd(&cursor[receivers[e]], 1);
        csr[p] = e;
    }
}

// One thread per CSR position: full edge math, dense lanes, bf16 row out.
__global__ __launch_bounds__(256) void edge_rows_kernel(
    const float* __restrict__ pos,
    const float* __restrict__ wr0, const float* __restrict__ wr1,
    const float* __restrict__ wr2, const float* __restrict__ wr3,
    const int* __restrict__ species,
    const int* __restrict__ senders,
    const int* __restrict__ receivers,
    const int* __restrict__ csr,
    int* __restrict__ spbuf,
    unsigned short* __restrict__ rows)
{
    int i = blockIdx.x * 256 + threadIdx.x;
    if (i >= NEDGES) return;
    const int e   = csr[i];
    const int snd = senders[e];
    const int rcv = receivers[e];
    const int sp  = species[snd];
    spbuf[i] = sp;

    float dx = pos[rcv*3]   - pos[snd*3];
    float dy = pos[rcv*3+1] - pos[snd*3+1];
    float dz = pos[rcv*3+2] - pos[snd*3+2];
    float r = sqrtf(dx*dx + dy*dy + dz*dz + 1e-12f);
    float inv_r = 1.0f / r;
    float x = dx * inv_r, y = dy * inv_r, z = dz * inv_r;

    float xr = fminf(r * 0.2f, 1.0f);
    float s1, c1;
    sincosf(3.14159265358979323846f * xr, &s1, &c1);
    float fcut = 0.5f * (c1 + 1.0f);
    float g = fcut / (xr + 0.001f);

    float bess[8];
    {
        float sm1 = 0.0f, s0 = s1;
        float tc = 2.0f * c1;
        #pragma unroll
        for (int n = 0; n < 8; ++n) {
            bess[n] = s0 * g;
            float s2 = tc * s0 - sm1;
            sm1 = s0; s0 = s2;
        }
    }

    float R0[8], R1[6], R2[4], R3[2];
    #pragma unroll
    for (int n = 0; n < 8; ++n) R0[n] = 0.0f;
    #pragma unroll
    for (int n = 0; n < 6; ++n) R1[n] = 0.0f;
    #pragma unroll
    for (int n = 0; n < 4; ++n) R2[n] = 0.0f;
    #pragma unroll
    for (int n = 0; n < 2; ++n) R3[n] = 0.0f;
    #pragma unroll
    for (int k = 0; k < 8; ++k) {
        float b = bess[k];
        #pragma unroll
        for (int n = 0; n < 8; ++n) R0[n] = fmaf(b, wr0[k*8 + n], R0[n]);
        #pragma unroll
        for (int n = 0; n < 6; ++n) R1[n] = fmaf(b, wr1[k*6 + n], R1[n]);
        #pragma unroll
        for (int n = 0; n < 4; ++n) R2[n] = fmaf(b, wr2[k*4 + n], R2[n]);
        #pragma unroll
        for (int n = 0; n < 2; ++n) R3[n] = fmaf(b, wr3[k*2 + n], R3[n]);
    }

    float xy = x*y, yz = y*z, xz = x*z;
    float x2 = x*x, y2 = y*y, z2 = z*z;
    float sh1v[3] = {0.4886025119029199f*y, 0.4886025119029199f*z, 0.4886025119029199f*x};
    float sh2v[5] = {1.0925484305920792f*xy, 1.0925484305920792f*yz,
                     0.31539156525252005f*(3.0f*z2 - 1.0f),
                     1.0925484305920792f*xz, 0.5462742152960396f*(x2 - y2)};
    float sh3v[7] = {0.5900435899266435f*y*(3.0f*x2 - y2),
                     2.890611442640554f*xy*z,
                     0.4570457994644658f*y*(5.0f*z2 - 1.0f),
                     0.3731763325901154f*z*(5.0f*z2 - 3.0f),
                     0.4570457994644658f*x*(5.0f*z2 - 1.0f),
                     1.445305721320277f*z*(x2 - y2),
                     0.5900435899266435f*x*(x2 - 3.0f*y2)};

    unsigned short h[60];
    #pragma unroll
    for (int n = 0; n < 8; ++n)
        h[n] = f2bf(R0[n] * 0.28209479177387814f);
    #pragma unroll
    for (int n = 0; n < 6; ++n)
        #pragma unroll
        for (int m = 0; m < 3; ++m)
            h[8 + n*3 + m] = f2bf(R1[n] * sh1v[m]);
    #pragma unroll
    for (int n = 0; n < 4; ++n)
        #pragma unroll
        for (int m = 0; m < 5; ++m)
            h[26 + n*5 + m] = f2bf(R2[n] * sh2v[m]);
    #pragma unroll
    for (int n = 0; n < 2; ++n)
        #pragma unroll
        for (int m = 0; m < 7; ++m)
            h[46 + n*7 + m] = f2bf(R3[n] * sh3v[m]);

    // 60 bf16 = 120 B per row, 8B-aligned: 15 x 8B stores
    uint2* dst = (uint2*)(rows + (size_t)i * 60);
    const uint2* src = (const uint2*)h;
    #pragma unroll
    for (int k = 0; k < 15; ++k) dst[k] = src[k];
}

__global__ __launch_bounds__(128) void atom_mix_kernel(
    const unsigned short* __restrict__ rows,
    const int* __restrict__ spbuf,
    const int* __restrict__ offsets,
    const float* __restrict__ W2,
    const float* __restrict__ emb2,
    const float* __restrict__ w_out,
    const float* __restrict__ comp_weights,
    const float* __restrict__ scaling,
    const int* __restrict__ species,
    const int* __restrict__ batch_seg,
    float* __restrict__ out)
{
    const int j    = threadIdx.x;   // 0..127 = K_MIX channel in phase 2
    const int w    = j >> 6;        // wave id (0/1)
    const int lane = j & 63;        // slot id in phase 1 (lanes 0..59 active)
    __shared__ float Tl[2][240];
    __shared__ float red[2];

    // persistent W2 column in registers
    float w2r0[32], w2r1[24], w2r2[16], w2r3[8];
    #pragma unroll
    for (int i = 0; i < 32; ++i) w2r0[i] = W2[i*128 + j];
    #pragma unroll
    for (int i = 0; i < 24; ++i) w2r1[i] = W2[4096 + i*128 + j];
    #pragma unroll
    for (int i = 0; i < 16; ++i) w2r2[i] = W2[7168 + i*128 + j];
    #pragma unroll
    for (int i = 0; i < 8;  ++i) w2r3[i] = W2[9216 + i*128 + j];
    const float wo   = w_out[j];
    const float scal = scaling[0];

    for (int atom = blockIdx.x; atom < NATOMS; atom += gridDim.x) {
        const int beg = offsets[atom];
        const int end = offsets[atom + 1];

        // phase 1: per-species register accumulation, wave w takes rows beg+w, beg+w+2, ...
        float a0 = 0.f, a1 = 0.f, a2 = 0.f, a3 = 0.f;
        if (lane < 60) {
            for (int i = beg + w; i < end; i += 2) {
                float v = bf2f(rows[(size_t)i * 60 + lane]);
                int sp = spbuf[i];
                a0 += (sp == 0) ? v : 0.0f;
                a1 += (sp == 1) ? v : 0.0f;
                a2 += (sp == 2) ? v : 0.0f;
                a3 += (sp == 3) ? v : 0.0f;
            }
        }
        __syncthreads();   // previous atom's phase 2 has finished reading Tl
        if (lane < 60) {
            Tl[w][lane]       = a0;
            Tl[w][60 + lane]  = a1;
            Tl[w][120 + lane] = a2;
            Tl[w][180 + lane] = a3;
        }
        __syncthreads();

        // phase 2: channel j mixing; Tl value = Tl[0][x] + Tl[1][x] (broadcast reads)
        float Bj = 0.0f;
        {
            float a = 0.0f;
            #pragma unroll
            for (int i = 0; i < 32; ++i) {
                const int t = (i >> 3)*60 + (i & 7);
                a = fmaf(w2r0[i], Tl[0][t] + Tl[1][t], a);
            }
            Bj += a * a;
        }
        {
            float a[3] = {0.f, 0.f, 0.f};
            #pragma unroll
            for (int i = 0; i < 24; ++i) {
                const int s = i / 6, n = i % 6;
                #pragma unroll
                for (int m = 0; m < 3; ++m) {
                    const int t = s*60 + 8 + n*3 + m;
                    a[m] = fmaf(w2r1[i], Tl[0][t] + Tl[1][t], a[m]);
                }
            }
            Bj += (a[0]*a[0] + a[1]*a[1] + a[2]*a[2]) * 0.57735026918962576f;
        }
        {
            float a[5] = {0.f, 0.f, 0.f, 0.f, 0.f};
            #pragma unroll
            for (int i = 0; i < 16; ++i) {
                const int s = i >> 2, n = i & 3;
                #pragma unroll
                for (int m = 0; m < 5; ++m) {
                    const int t = s*60 + 26 + n*5 + m;
                    a[m] = fmaf(w2r2[i], Tl[0][t] + Tl[1][t], a[m]);
                }
            }
            float ss = a[0]*a[0] + a[1]*a[1] + a[2]*a[2] + a[3]*a[3] + a[4]*a[4];
            Bj += ss * 0.44721359549995794f;
        }
        {
            float a[7] = {0.f, 0.f, 0.f, 0.f, 0.f, 0.f, 0.f};
            #pragma unroll
            for (int i = 0; i < 8; ++i) {
                const int s = i >> 1, n = i & 1;
                #pragma unroll
                for (int m = 0; m < 7; ++m) {
                    const int t = s*60 + 46 + n*7 + m;
                    a[m] = fmaf(w2r3[i], Tl[0][t] + Tl[1][t], a[m]);
                }
            }
            float ss = 0.0f;
            #pragma unroll
            for (int m = 0; m < 7; ++m) ss = fmaf(a[m], a[m], ss);
            Bj += ss * 0.37796447300922725f;
        }

        const int sp = species[atom];
        float B4 = Bj * Bj;
        float v = B4 * emb2[sp*128 + j] * wo;

        #pragma unroll
        for (int o = 32; o > 0; o >>= 1) v += __shfl_down(v, o, 64);
        if (lane == 0) red[w] = v;
        __syncthreads();
        if (j == 0) {
            float at = fmaf(red[0] + red[1], scal, comp_weights[sp]);
            atomicAdd(&out[batch_seg[atom]], at);
        }
    }
}

extern "C" void kernel_launch(void* const* d_in, const int* in_sizes, int n_in,
                              void* d_out, int out_size, void* d_ws, size_t ws_size,
                              hipStream_t stream)
{
    const float* pos  = (const float*)d_in[0];
    const float* emb  = (const float*)d_in[1];
    const float* wr0  = (const float*)d_in[2];
    const float* wm0  = (const float*)d_in[3];
    const float* wr1  = (const float*)d_in[4];
    const float* wm1  = (const float*)d_in[5];
    const float* wr2  = (const float*)d_in[6];
    const float* wm2  = (const float*)d_in[7];
    const float* wr3  = (const float*)d_in[8];
    const float* wm3  = (const float*)d_in[9];
    const float* emb2 = (const float*)d_in[10];
    const float* wout = (const float*)d_in[11];
    const float* cw   = (const float*)d_in[12];
    const float* scal = (const float*)d_in[13];
    const int* species   = (const int*)d_in[14];
    const int* senders   = (const int*)d_in[15];
    const int* receivers = (const int*)d_in[16];
    const int* batch_seg = (const int*)d_in[17];

    int* counts  = (int*)d_ws;                    // 10016
    int* offsets = counts + 10016;                // 10016
    int* cursor  = offsets + 10016;               // 10016
    int* csr     = cursor + 10016;                // 200000
    int* spbuf   = csr + 200000;                  // 200000
    float* W2    = (float*)(spbuf + 200000);      // 10240 floats
    unsigned short* rows = (unsigned short*)(W2 + 10240); // 200000*60 bf16 = 24 MB

    hipMemsetAsync(counts, 0, 10000 * sizeof(int), stream);
    hipMemsetAsync(d_out, 0, (size_t)out_size * sizeof(float), stream);

    prep_w2_kernel<<<40, 256, 0, stream>>>(emb, wm0, wm1, wm2, wm3, W2);
    count_kernel<<<(NEDGES + 255)/256, 256, 0, stream>>>(receivers, counts);
    scan_kernel<<<1, 1024, 0, stream>>>(counts, offsets, cursor);
    scatter_kernel<<<(NEDGES + 255)/256, 256, 0, stream>>>(receivers, cursor, csr);
    edge_rows_kernel<<<(NEDGES + 255)/256, 256, 0, stream>>>(
        pos, wr0, wr1, wr2, wr3, species, senders, receivers, csr, spbuf, rows);
    atom_mix_kernel<<<2000, 128, 0, stream>>>(
        rows, spbuf, offsets, W2, emb2, wout, cw, scal, species, batch_seg,
        (float*)d_out);
}